// Round 6
// baseline (193.446 us; speedup 1.0000x reference)
//
#include <hip/hip_runtime.h>
#include <stdint.h>

#define NB 32
#define NT 2000
#define NH 256
#define NS 63
#define LDSROW 264   // padded bf16 row stride (528 B)

typedef __attribute__((ext_vector_type(8))) short bf16x8;
typedef __attribute__((ext_vector_type(4))) float f32x4;

__device__ inline unsigned short f2bf(float f) {
  union { float f; uint32_t u; } v; v.f = f;
  return (unsigned short)((v.u + 0x7fffu + ((v.u >> 16) & 1u)) >> 16);  // RNE
}

// W1 (512x256 f32) -> W1T bf16 [256][512]; W2 (256x63) -> W2T bf16 [64][256].
__global__ __launch_bounds__(256) void convert_kernel(
    const float* __restrict__ W1, const float* __restrict__ W2,
    unsigned short* __restrict__ W1T, unsigned short* __restrict__ W2T) {
  __shared__ unsigned short sm[64 * 264];
  const int tid = threadIdx.x;
  if (blockIdx.x < 32) {
    const int k0 = (blockIdx.x >> 2) * 64;
    const int n0 = (blockIdx.x & 3) * 64;
    #pragma unroll
    for (int it = 0; it < 4; ++it) {
      int i = tid + it * 256;
      int kk = i >> 4, c4 = (i & 15) * 4;
      float4 v = *(const float4*)&W1[(size_t)(k0 + kk) * NH + n0 + c4];
      sm[(c4 + 0) * 72 + kk] = f2bf(v.x);
      sm[(c4 + 1) * 72 + kk] = f2bf(v.y);
      sm[(c4 + 2) * 72 + kk] = f2bf(v.z);
      sm[(c4 + 3) * 72 + kk] = f2bf(v.w);
    }
    __syncthreads();
    #pragma unroll
    for (int it = 0; it < 2; ++it) {
      int j = tid + it * 256;
      int r = j >> 3, c8 = (j & 7) * 8;
      bf16x8 v = *(const bf16x8*)&sm[r * 72 + c8];
      *(bf16x8*)&W1T[(size_t)(n0 + r) * 512 + k0 + c8] = v;
    }
  } else {
    for (int i = tid; i < 256 * 64; i += 256) {
      int k = i >> 6, n = i & 63;
      float val = (n < NS) ? W2[k * NS + n] : 0.f;
      sm[n * 264 + k] = f2bf(val);
    }
    __syncthreads();
    #pragma unroll
    for (int it = 0; it < 8; ++it) {
      int j = tid + it * 256;
      int n = j >> 5, c8 = (j & 31) * 8;
      bf16x8 v = *(const bf16x8*)&sm[n * 264 + c8];
      *(bf16x8*)&W2T[(size_t)n * 256 + c8] = v;
    }
  }
}

// Fused: block (i, b) computes trans rows base..base+63 (base = 63*i - 1) into
// LDS, then softmax for t in [63*i, 63*i+62]. trans never touches global.
__global__ __launch_bounds__(256, 3) void fused_kernel(
    const float* __restrict__ E, const float* __restrict__ logits,
    const int* __restrict__ kw, const unsigned short* __restrict__ W1T,
    const float* __restrict__ b1, const unsigned short* __restrict__ W2T,
    const float* __restrict__ b2, float* __restrict__ out) {
  const int b = blockIdx.y;
  const int a0 = blockIdx.x * 63;     // first align t of this block
  const int base = a0 - 1;            // first trans row computed
  const int tid = threadIdx.x;
  const int w = tid >> 6;
  const int lane = tid & 63;
  const int quad = lane >> 4;
  const int l16 = lane & 15;
  const int n0 = w * 64;

  __shared__ unsigned short lds[65 * LDSROW];           // 34320 B
  float* TRf = (float*)lds;                             // [64][68] f32 (17408 B)
  float* LPf = (float*)((char*)lds + 17408);            // [64][64] f32 (16384 B)

  // W1T first B-frags before staging (hide L2 latency under E loads)
  bf16x8 bc[4];
  #pragma unroll
  for (int tn = 0; tn < 4; ++tn)
    bc[tn] = *(const bf16x8*)&W1T[(size_t)(n0 + tn * 16 + l16) * 512 + quad * 8];

  // Stage E rows base..base+64 (clamped to [0, NT-1]), f32 -> bf16
  const float* Eb = E + (size_t)b * NT * NH;
  for (int i = tid; i < 65 * 64; i += 256) {
    int row = i >> 6, c4 = (i & 63) << 2;
    int tr = base + row;
    tr = (tr < 0) ? 0 : (tr > NT - 1 ? NT - 1 : tr);
    float4 v = *(const float4*)&Eb[(size_t)tr * NH + c4];
    ushort4 o;
    o.x = f2bf(v.x); o.y = f2bf(v.y); o.z = f2bf(v.z); o.w = f2bf(v.w);
    *(ushort4*)&lds[row * LDSROW + c4] = o;
  }
  __syncthreads();

  // GEMM1: h[m][n] = e[base+m+1]@W1_top + e[base+m]@W1_bot
  f32x4 acc[4][4];
  #pragma unroll
  for (int tm = 0; tm < 4; ++tm)
    #pragma unroll
    for (int tn = 0; tn < 4; ++tn) acc[tm][tn] = (f32x4){0.f, 0.f, 0.f, 0.f};

  #pragma unroll
  for (int km = 0; km < 16; ++km) {
    const int aoff = (km >> 3) ? 0 : 1;
    bf16x8 bn[4];
    if (km < 15) {
      const int km2 = km + 1, h2 = km2 >> 3, k02 = (km2 & 7) * 32;
      #pragma unroll
      for (int tn = 0; tn < 4; ++tn)
        bn[tn] = *(const bf16x8*)&W1T[(size_t)(n0 + tn * 16 + l16) * 512 +
                                      h2 * 256 + k02 + quad * 8];
    }
    bf16x8 af[4];
    #pragma unroll
    for (int tm = 0; tm < 4; ++tm)
      af[tm] = *(const bf16x8*)&lds[(tm * 16 + l16 + aoff) * LDSROW +
                                    (km & 7) * 32 + quad * 8];
    #pragma unroll
    for (int tm = 0; tm < 4; ++tm)
      #pragma unroll
      for (int tn = 0; tn < 4; ++tn)
        acc[tm][tn] = __builtin_amdgcn_mfma_f32_16x16x32_bf16(
            af[tm], bc[tn], acc[tm][tn], 0, 0, 0);
    if (km < 15) {
      #pragma unroll
      for (int tn = 0; tn < 4; ++tn) bc[tn] = bn[tn];
    }
  }

  bf16x8 b2c[4];
  #pragma unroll
  for (int tn = 0; tn < 4; ++tn)
    b2c[tn] = *(const bf16x8*)&W2T[(size_t)(tn * 16 + l16) * 256 + quad * 8];

  __syncthreads();  // GEMM1 A-reads done

  // h = relu(acc + b1) -> bf16 LDS rows 0..63
  #pragma unroll
  for (int tn = 0; tn < 4; ++tn) {
    float b1v = b1[n0 + tn * 16 + l16];
    #pragma unroll
    for (int tm = 0; tm < 4; ++tm)
      #pragma unroll
      for (int r = 0; r < 4; ++r) {
        float hv = fmaxf(acc[tm][tn][r] + b1v, 0.f);
        lds[(tm * 16 + quad * 4 + r) * LDSROW + n0 + tn * 16 + l16] = f2bf(hv);
      }
  }
  __syncthreads();

  // GEMM2: wave w -> trans rows m0..m0+15 (all 64 padded s-cols)
  const int m0 = w * 16;
  f32x4 acc2[4];
  #pragma unroll
  for (int tn = 0; tn < 4; ++tn) acc2[tn] = (f32x4){0.f, 0.f, 0.f, 0.f};

  #pragma unroll
  for (int ks = 0; ks < 8; ++ks) {
    const int k0 = ks * 32;
    bf16x8 b2n[4];
    if (ks < 7) {
      #pragma unroll
      for (int tn = 0; tn < 4; ++tn)
        b2n[tn] = *(const bf16x8*)&W2T[(size_t)(tn * 16 + l16) * 256 +
                                       (k0 + 32) + quad * 8];
    }
    bf16x8 af = *(const bf16x8*)&lds[(m0 + l16) * LDSROW + k0 + quad * 8];
    #pragma unroll
    for (int tn = 0; tn < 4; ++tn)
      acc2[tn] = __builtin_amdgcn_mfma_f32_16x16x32_bf16(af, b2c[tn], acc2[tn], 0, 0, 0);
    if (ks < 7) {
      #pragma unroll
      for (int tn = 0; tn < 4; ++tn) b2c[tn] = b2n[tn];
    }
  }
  __syncthreads();  // all h reads done; LDS now reused for TR + LP

  // TR[m][s] = trans row (base+m); pad col 63 = 0-bias garbage (never read)
  #pragma unroll
  for (int tn = 0; tn < 4; ++tn) {
    int s = tn * 16 + l16;
    float b2v = (s < NS) ? b2[s] : 0.f;
    #pragma unroll
    for (int r = 0; r < 4; ++r)
      TRf[(m0 + quad * 4 + r) * 68 + s] = acc2[tn][r] + b2v;
  }

  // Stage logits rows a0..a0+63 (clamped) -> LP[j][lane]
  const float* lb = logits + (size_t)b * NT * NS;
  #pragma unroll
  for (int rr = 0; rr < 16; ++rr) {
    int j = w * 16 + rr;
    int t = a0 + j; if (t > NT - 1) t = NT - 1;
    if (lane < NS) LPf[j * 64 + lane] = lb[(size_t)t * NS + lane];
  }
  __syncthreads();

  // Softmax for t = a0 + j, j in [0, 62]
  for (int rr = 0; rr < 16; ++rr) {
    const int j = w * 16 + rr;
    const int t = a0 + j;
    if (j == 63 || t > NT - 1) continue;
    float sc;
    if (t == 0) {
      // f0 = LP[0][kw] - LSE(LP[0]); score = f0*[lane==0] + LP[1] + TR[1]
      float v = (lane < NS) ? LPf[lane] : -1e30f;
      float m = v;
      #pragma unroll
      for (int o = 32; o > 0; o >>= 1) m = fmaxf(m, __shfl_xor(m, o));
      float ee = (lane < NS) ? __expf(v - m) : 0.f;
      float ss = ee;
      #pragma unroll
      for (int o = 32; o > 0; o >>= 1) ss += __shfl_xor(ss, o);
      const float lse = m + __logf(ss);
      const float f00 = LPf[kw[b * 32]] - lse;
      sc = ((lane == 0) ? f00 : 0.f) + LPf[64 + lane] + TRf[68 + lane];
    } else if (t == NT - 1) {
      sc = LPf[j * 64 + lane] + TRf[j * 68 + lane];
    } else {
      sc = LPf[j * 64 + lane] + LPf[(j + 1) * 64 + lane] +
           TRf[j * 68 + lane] + TRf[(j + 1) * 68 + lane];
    }
    float e = (lane < NS) ? __expf(sc) : 0.f;
    float s = e;
    #pragma unroll
    for (int o = 32; o > 0; o >>= 1) s += __shfl_xor(s, o);
    if (lane < NS) out[((size_t)b * NT + t) * NS + lane] = e / s;
  }
}

extern "C" void kernel_launch(void* const* d_in, const int* in_sizes, int n_in,
                              void* d_out, int out_size, void* d_ws, size_t ws_size,
                              hipStream_t stream) {
  const float* logits = (const float*)d_in[0];
  const float* E      = (const float*)d_in[1];
  const int*   kw     = (const int*)d_in[2];
  const float* W1     = (const float*)d_in[3];
  const float* b1     = (const float*)d_in[4];
  const float* W2     = (const float*)d_in[5];
  const float* b2     = (const float*)d_in[6];
  float* out = (float*)d_out;

  unsigned short* W1T = (unsigned short*)d_ws;          // 256x512 bf16
  unsigned short* W2T = W1T + 512 * 256;                // 64x256 bf16

  convert_kernel<<<33, 256, 0, stream>>>(W1, W2, W1T, W2T);
  dim3 g(32, NB);  // 32 t-blocks (63 t's each) x 32 batches = 1024 blocks
  fused_kernel<<<g, 256, 0, stream>>>(E, logits, kw, W1T, b1, W2T, b2, out);
}

// Round 8
// 169.162 us; speedup vs baseline: 1.1436x; 1.1436x over previous
//
#include <hip/hip_runtime.h>
#include <stdint.h>

#define NB 32
#define NT 2000
#define NH 256
#define NS 63
#define LDSROW 264   // padded bf16 row stride (528 B)

typedef __attribute__((ext_vector_type(8))) short bf16x8;
typedef __attribute__((ext_vector_type(4))) float f32x4;

__device__ inline unsigned short f2bf(float f) {
  union { float f; uint32_t u; } v; v.f = f;
  return (unsigned short)((v.u + 0x7fffu + ((v.u >> 16) & 1u)) >> 16);  // RNE
}
__device__ inline unsigned int pk2(float a, float b) {
  return (unsigned int)f2bf(a) | ((unsigned int)f2bf(b) << 16);
}
__device__ inline bf16x8 pack8(const float* g) {
  union { bf16x8 v; unsigned int u[4]; } c;
  c.u[0] = pk2(g[0], g[1]); c.u[1] = pk2(g[2], g[3]);
  c.u[2] = pk2(g[4], g[5]); c.u[3] = pk2(g[6], g[7]);
  return c.v;
}

// ONE kernel, 256 threads (4 waves), R6's proven 64-row geometry.
// Block (i, b): trans rows base..base+63 (base = 63*i - 1) in LDS via two MFMA
// GEMMs (B gathered from f32 W1/W2 on the fly), then softmax for
// t in [63*i, 63*i+62]. LP is a SEPARATE LDS array (no overlay with h);
// TR reuses the h region only after the "h reads done" barrier (as in R6).
__global__ __launch_bounds__(256, 3) void fused_kernel(
    const float* __restrict__ E, const float* __restrict__ logits,
    const int* __restrict__ kw, const float* __restrict__ W1,
    const float* __restrict__ b1, const float* __restrict__ W2,
    const float* __restrict__ b2, float* __restrict__ out) {
  const int b = blockIdx.y;
  const int a0 = blockIdx.x * 63;   // first align t of this block
  const int base = a0 - 1;          // first trans row computed
  const int tid = threadIdx.x;
  const int w = tid >> 6;
  const int lane = tid & 63;
  const int quad = lane >> 4;
  const int l16 = lane & 15;
  const int n0 = w * 64;

  __shared__ unsigned short lds[65 * LDSROW];  // 34320 B: E-tile -> h -> TR
  __shared__ float LPs[64 * 64];               // 16384 B: logits rows (separate!)
  float* TRf = (float*)lds;                    // [64][68] f32 (17408 B, in h region)

  // Stage E rows base..base+64 (clamped to [0, NT-1]), f32 -> bf16
  const float* Eb = E + (size_t)b * NT * NH;
  for (int i = tid; i < 65 * 64; i += 256) {
    int row = i >> 6, c4 = (i & 63) << 2;
    int tr = base + row;
    tr = (tr < 0) ? 0 : (tr > NT - 1 ? NT - 1 : tr);
    float4 v = *(const float4*)&Eb[(size_t)tr * NH + c4];
    ushort4 o;
    o.x = f2bf(v.x); o.y = f2bf(v.y); o.z = f2bf(v.z); o.w = f2bf(v.w);
    *(ushort4*)&lds[row * LDSROW + c4] = o;
  }
  // Stage logits rows a0..a0+63 early (latency hides under GEMM1).
  // Every cell initialized (col 63 = clamped copy, never used numerically).
  const float* lb = logits + (size_t)b * NT * NS;
  for (int i = tid; i < 64 * 64; i += 256) {
    int j = i >> 6, c = i & 63;
    int t = a0 + j; if (t > NT - 1) t = NT - 1;
    int cc = (c < NS) ? c : NS - 1;
    LPs[i] = lb[(size_t)t * NS + cc];
  }
  __syncthreads();

  // GEMM1: h[m][n] = e[base+m+1]@W1_top + e[base+m]@W1_bot  (m = 0..63,
  // wave w owns cols n0..n0+63; B gathered from f32 W1, tn-pipelined)
  f32x4 acc[4][4];
  #pragma unroll
  for (int tm = 0; tm < 4; ++tm)
    #pragma unroll
    for (int tn = 0; tn < 4; ++tn) acc[tm][tn] = (f32x4){0.f, 0.f, 0.f, 0.f};

  const float* w1p = W1 + (size_t)(quad * 8) * NH + n0 + l16;

  #pragma unroll
  for (int km = 0; km < 16; ++km) {
    const int hk = (km >> 3) * 256 + (km & 7) * 32;  // k in [0,512)
    const int aoff = (km >> 3) ? 0 : 1;              // top half pairs e[t+1]

    bf16x8 af[4];
    #pragma unroll
    for (int tm = 0; tm < 4; ++tm)
      af[tm] = *(const bf16x8*)&lds[(tm * 16 + l16 + aoff) * LDSROW +
                                    (km & 7) * 32 + quad * 8];

    float g[8], gn[8];
    #pragma unroll
    for (int j = 0; j < 8; ++j) g[j] = w1p[(size_t)(hk + j) * NH];
    #pragma unroll
    for (int tn = 0; tn < 4; ++tn) {
      if (tn < 3) {
        #pragma unroll
        for (int j = 0; j < 8; ++j)
          gn[j] = w1p[(size_t)(hk + j) * NH + (tn + 1) * 16];
      }
      bf16x8 bq = pack8(g);
      #pragma unroll
      for (int tm = 0; tm < 4; ++tm)
        acc[tm][tn] = __builtin_amdgcn_mfma_f32_16x16x32_bf16(
            af[tm], bq, acc[tm][tn], 0, 0, 0);
      if (tn < 3) {
        #pragma unroll
        for (int j = 0; j < 8; ++j) g[j] = gn[j];
      }
    }
  }
  __syncthreads();  // GEMM1 A-reads done

  // h = relu(acc + b1) -> bf16 LDS rows 0..63
  #pragma unroll
  for (int tn = 0; tn < 4; ++tn) {
    float b1v = b1[n0 + tn * 16 + l16];
    #pragma unroll
    for (int tm = 0; tm < 4; ++tm)
      #pragma unroll
      for (int r = 0; r < 4; ++r) {
        float hv = fmaxf(acc[tm][tn][r] + b1v, 0.f);
        lds[(tm * 16 + quad * 4 + r) * LDSROW + n0 + tn * 16 + l16] = f2bf(hv);
      }
  }
  __syncthreads();

  // GEMM2: wave w -> trans rows m0..m0+15; B gathered from f32 W2 (col 63 -> 0)
  const int m0 = w * 16;
  f32x4 acc2[4];
  #pragma unroll
  for (int tn = 0; tn < 4; ++tn) acc2[tn] = (f32x4){0.f, 0.f, 0.f, 0.f};

  #pragma unroll
  for (int ks = 0; ks < 8; ++ks) {
    const int k0 = ks * 32;
    bf16x8 af = *(const bf16x8*)&lds[(m0 + l16) * LDSROW + k0 + quad * 8];
    #pragma unroll
    for (int tn = 0; tn < 4; ++tn) {
      const int n = tn * 16 + l16;
      float g[8];
      #pragma unroll
      for (int j = 0; j < 8; ++j)
        g[j] = (n < NS) ? W2[(size_t)(k0 + quad * 8 + j) * NS + n] : 0.f;
      bf16x8 bq = pack8(g);
      acc2[tn] = __builtin_amdgcn_mfma_f32_16x16x32_bf16(af, bq, acc2[tn], 0, 0, 0);
    }
  }
  __syncthreads();  // all h reads done; h region now reused for TR

  // TR[m][s] = trans[base+m][s] (f32); col 63 = 0 (defined, never used)
  #pragma unroll
  for (int tn = 0; tn < 4; ++tn) {
    int s = tn * 16 + l16;
    float b2v = (s < NS) ? b2[s] : 0.f;
    #pragma unroll
    for (int r = 0; r < 4; ++r)
      TRf[(m0 + quad * 4 + r) * 68 + s] = acc2[tn][r] + b2v;
  }
  __syncthreads();

  // Softmax for t = a0 + j, j in [0, 62]  (scores bounded -> max-free softmax)
  for (int rr = 0; rr < 16; ++rr) {
    const int j = m0 + rr;
    const int t = a0 + j;
    if (j == 63 || t > NT - 1) continue;
    float sc;
    if (t == 0) {
      float v = (lane < NS) ? LPs[lane] : -1e30f;
      float m = v;
      #pragma unroll
      for (int o = 32; o > 0; o >>= 1) m = fmaxf(m, __shfl_xor(m, o));
      float ee = (lane < NS) ? __expf(v - m) : 0.f;
      float ss = ee;
      #pragma unroll
      for (int o = 32; o > 0; o >>= 1) ss += __shfl_xor(ss, o);
      const float lse = m + __logf(ss);
      const float f00 = LPs[kw[b * 32]] - lse;
      sc = ((lane == 0) ? f00 : 0.f) + LPs[64 + lane] + TRf[68 + lane];
    } else if (t == NT - 1) {
      sc = LPs[j * 64 + lane] + TRf[j * 68 + lane];
    } else {
      sc = LPs[j * 64 + lane] + LPs[(j + 1) * 64 + lane] +
           TRf[j * 68 + lane] + TRf[(j + 1) * 68 + lane];
    }
    float e = (lane < NS) ? __expf(sc) : 0.f;
    float s = e;
    #pragma unroll
    for (int o = 32; o > 0; o >>= 1) s += __shfl_xor(s, o);
    if (lane < NS) out[((size_t)b * NT + t) * NS + lane] = e / s;
  }
}

extern "C" void kernel_launch(void* const* d_in, const int* in_sizes, int n_in,
                              void* d_out, int out_size, void* d_ws, size_t ws_size,
                              hipStream_t stream) {
  const float* logits = (const float*)d_in[0];
  const float* E      = (const float*)d_in[1];
  const int*   kw     = (const int*)d_in[2];
  const float* W1     = (const float*)d_in[3];
  const float* b1     = (const float*)d_in[4];
  const float* W2     = (const float*)d_in[5];
  const float* b2     = (const float*)d_in[6];
  float* out = (float*)d_out;

  dim3 g(32, NB);  // 32 t-blocks (63 t's each) x 32 batches = 1024 blocks
  fused_kernel<<<g, 256, 0, stream>>>(E, logits, kw, W1, b1, W2, b2, out);
}